// Round 3
// baseline (586.281 us; speedup 1.0000x reference)
//
#include <hip/hip_runtime.h>
#include <math.h>

constexpr int N_NODES = 50000;
constexpr int N_PAD   = 50048;    // 391 * 128, padded rows for tile overrun
constexpr int N_EDGES = 400000;
constexpr int IN_F = 512;
constexpr int HEADS = 8;
constexpr int OUT_F = 64;
constexpr int HF = 512;           // HEADS * OUT_F
constexpr float NEG = 0.2f;

typedef __bf16 bf16x8 __attribute__((ext_vector_type(8)));
typedef float  f32x4  __attribute__((ext_vector_type(4)));

__device__ __forceinline__ unsigned short f2bf(float f) {
    unsigned u = __float_as_uint(f);
    u += 0x7fffu + ((u >> 16) & 1u);   // round-to-nearest-even (inputs finite)
    return (unsigned short)(u >> 16);
}
__device__ __forceinline__ unsigned packbf2(float lo, float hi) {
    return (unsigned)f2bf(lo) | ((unsigned)f2bf(hi) << 16);
}

// ---------------------------------------------------------------------------
// K0: feat fp32 -> bf16; tail blocks zero denom and deg.
// ---------------------------------------------------------------------------
constexpr int K0_CONV_BLOCKS = 12500;                 // 12500*256*8 = 25.6M elems
constexpr int K0_ZERO_BLOCKS = (N_EDGES + 255) / 256; // 1563: covers 400000 denom + 50000 deg

__global__ __launch_bounds__(256) void k0_convert(const float* __restrict__ in,
                                                  unsigned short* __restrict__ out,
                                                  float* __restrict__ denom,
                                                  int* __restrict__ deg) {
    int b = blockIdx.x;
    if (b < K0_CONV_BLOCKS) {
        int idx = b * 256 + threadIdx.x;
        size_t base = (size_t)idx * 8;
        float4 a = *(const float4*)(in + base);
        float4 c = *(const float4*)(in + base + 4);
        uint4 v;
        v.x = packbf2(a.x, a.y);
        v.y = packbf2(a.z, a.w);
        v.z = packbf2(c.x, c.y);
        v.w = packbf2(c.z, c.w);
        *(uint4*)(out + base) = v;
    } else {
        int idx = (b - K0_CONV_BLOCKS) * 256 + threadIdx.x;
        if (idx < N_NODES * 8) denom[idx] = 0.f;
        if (idx < N_NODES) deg[idx] = 0;
    }
}

// ---------------------------------------------------------------------------
// K14: merged dispatch — [0,256): W_val transpose->bf16; [256,289): fold
// attention vectors; [289,...): dst-degree histogram.
// ---------------------------------------------------------------------------
constexpr int K14_HIST0 = 289;
constexpr int K14_BLOCKS = K14_HIST0 + (N_EDGES + 255) / 256;   // 289 + 1563

__global__ __launch_bounds__(256) void k14_misc(
        const float* __restrict__ W_val, unsigned short* __restrict__ Wt,
        const float* __restrict__ W_src, const float* __restrict__ b_src,
        const float* __restrict__ W_dst, const float* __restrict__ b_dst,
        const float* __restrict__ attn_l, const float* __restrict__ attn_r,
        float* __restrict__ w_l, float* __restrict__ w_r,
        float* __restrict__ c_l, float* __restrict__ c_r,
        const int* __restrict__ dst, int* __restrict__ deg) {
    __shared__ float tile[32][33];
    int b = blockIdx.x, t = threadIdx.x;
    if (b < 256) {
        // W_val fp32 [K][N] -> Wt bf16 [N][K]
        int bi = b >> 4, bj = b & 15;
        for (int i = t; i < 1024; i += 256) {
            int r = i >> 5, c = i & 31;
            tile[r][c] = W_val[(size_t)(bi * 32 + r) * HF + bj * 32 + c];
        }
        __syncthreads();
        for (int i = t; i < 1024; i += 256) {
            int r = i >> 5, c = i & 31;
            Wt[(size_t)(bj * 32 + r) * IN_F + bi * 32 + c] = f2bf(tile[c][r]);
        }
    } else if (b < K14_HIST0) {
        int gid = (b - 256) * 256 + t;
        if (gid < 4096) {
            int k = gid >> 3, h = gid & 7;
            float s = 0.f;
            #pragma unroll 8
            for (int f = 0; f < OUT_F; ++f) s += W_src[k * HF + h * OUT_F + f] * attn_l[h * OUT_F + f];
            w_l[k * 8 + h] = s;
        } else if (gid < 8192) {
            int g = gid - 4096;
            int k = g >> 3, h = g & 7;
            float s = 0.f;
            #pragma unroll 8
            for (int f = 0; f < OUT_F; ++f) s += W_dst[k * HF + h * OUT_F + f] * attn_r[h * OUT_F + f];
            w_r[k * 8 + h] = s;
        } else if (gid < 8192 + 16) {
            int g = gid - 8192;
            int h = g & 7;
            float s = 0.f;
            if (g < 8) {
                for (int f = 0; f < OUT_F; ++f) s += b_src[h * OUT_F + f] * attn_l[h * OUT_F + f];
                c_l[h] = s;
            } else {
                for (int f = 0; f < OUT_F; ++f) s += b_dst[h * OUT_F + f] * attn_r[h * OUT_F + f];
                c_r[h] = s;
            }
        }
    } else {
        int e = (b - K14_HIST0) * 256 + t;
        if (e < N_EDGES) atomicAdd(&deg[dst[e]], 1);
    }
}

// ---------------------------------------------------------------------------
// K2: el/er = feat @ w_l/w_r + c. 16 threads per node; w in LDS
// (same-address broadcast across nodes -> conflict-free).
// ---------------------------------------------------------------------------
__global__ __launch_bounds__(256) void k2_el_er(
        const float* __restrict__ feat,
        const float* __restrict__ w_l, const float* __restrict__ w_r,
        const float* __restrict__ c_l, const float* __restrict__ c_r,
        float* __restrict__ el, float* __restrict__ er) {
    __shared__ float swl[4096];
    __shared__ float swr[4096];
    int t = threadIdx.x;
    for (int i = t; i < 4096; i += 256) { swl[i] = w_l[i]; swr[i] = w_r[i]; }
    __syncthreads();

    int node = blockIdx.x * 16 + (t >> 4);
    if (node >= N_NODES) return;
    int sub = t & 15, h = sub & 7, side = sub >> 3;

    const float* w = side ? swr : swl;
    float acc = side ? c_r[h] : c_l[h];
    const float* frow = feat + (size_t)node * IN_F;
    for (int k = 0; k < IN_F; k += 4) {
        float4 f = *(const float4*)(frow + k);
        acc = fmaf(f.x, w[(k + 0) * 8 + h], acc);
        acc = fmaf(f.y, w[(k + 1) * 8 + h], acc);
        acc = fmaf(f.z, w[(k + 2) * 8 + h], acc);
        acc = fmaf(f.w, w[(k + 3) * 8 + h], acc);
    }
    if (side) er[node * 8 + h] = acc; else el[node * 8 + h] = acc;
}

// ---------------------------------------------------------------------------
// KS: single-dispatch exclusive scan. 49 blocks; each block redundantly sums
// its prefix range (O(n^2/2) = 4.9 MB of L2-resident reads — cheap), then
// scans its own 1024 elements locally. No serial block, no cross-block sync.
// ---------------------------------------------------------------------------
__global__ __launch_bounds__(1024) void kS_scan(const int* __restrict__ deg,
                                                int* __restrict__ offs,
                                                int* __restrict__ cursor) {
    __shared__ int wsum[16];
    __shared__ int base_s;
    int b = blockIdx.x, t = threadIdx.x;
    int lane = t & 63, wid = t >> 6;

    // 1) base = sum deg[0 .. b*1024)
    int pre = 0;
    for (int i = t; i < b * 1024; i += 1024) pre += deg[i];
    #pragma unroll
    for (int off = 32; off; off >>= 1) pre += __shfl_down(pre, (unsigned)off, 64);
    if (lane == 0) wsum[wid] = pre;
    __syncthreads();
    if (t == 0) {
        int s = 0;
        for (int i = 0; i < 16; ++i) s += wsum[i];
        base_s = s;
    }
    __syncthreads();
    int base = base_s;
    __syncthreads();

    // 2) local exclusive scan of elements [b*1024, b*1024+1024)
    int i = b * 1024 + t;
    int v = (i < N_NODES) ? deg[i] : 0;
    int x = v;
    #pragma unroll
    for (int off = 1; off < 64; off <<= 1) {
        int y = __shfl_up(x, (unsigned)off, 64);
        if (lane >= off) x += y;
    }
    if (lane == 63) wsum[wid] = x;
    __syncthreads();
    if (wid == 0) {
        int s = (lane < 16) ? wsum[lane] : 0;
        #pragma unroll
        for (int off = 1; off < 16; off <<= 1) {
            int y = __shfl_up(s, (unsigned)off, 64);
            if (lane >= off) s += y;
        }
        if (lane < 16) wsum[lane] = s;
    }
    __syncthreads();
    int woff = wid ? wsum[wid - 1] : 0;
    if (i < N_NODES) {
        int excl = base + woff + x - v;
        offs[i] = excl;
        cursor[i] = excl;
    }
}

// ---------------------------------------------------------------------------
// K3: feat_v = feat @ W_val + b_val via bf16 MFMA (m97 structure, validated R2)
// ---------------------------------------------------------------------------
__global__ __launch_bounds__(256) void k3_mfma(
        const unsigned short* __restrict__ Abf,   // feat bf16 [N_PAD][512]
        const unsigned short* __restrict__ Bbf,   // Wt bf16 [512][512] (n-major)
        const float* __restrict__ bias,
        unsigned short* __restrict__ C) {         // feat_v bf16 [N_PAD][512]
    __shared__ unsigned short As[128 * 64];
    __shared__ unsigned short Bs[128 * 64];
    int tid = threadIdx.x;
    int w = tid >> 6, lane = tid & 63;
    int bm = blockIdx.x >> 2, bn = blockIdx.x & 3;
    int rowBase = bm * 128, colBase = bn * 128;
    int wm = w >> 1, wn = w & 1;
    int c15 = lane & 15, q = lane >> 4;

    f32x4 acc[4][4] = {};

    for (int k0 = 0; k0 < IN_F; k0 += 64) {
        #pragma unroll
        for (int rnd = 0; rnd < 4; ++rnd) {
            int e = w * 256 + rnd * 64 + lane;     // chunk index 0..1023
            int r = e >> 3, p = e & 7;
            int lc = p ^ (r & 7);                  // XOR chunk swizzle
            const unsigned short* gA = Abf + (size_t)(rowBase + r) * IN_F + k0 + lc * 8;
            unsigned short* lA = &As[(w * 256 + rnd * 64) * 8];
            __builtin_amdgcn_global_load_lds(
                (const __attribute__((address_space(1))) unsigned int*)gA,
                (__attribute__((address_space(3))) unsigned int*)lA, 16, 0, 0);
            const unsigned short* gB = Bbf + (size_t)(colBase + r) * IN_F + k0 + lc * 8;
            unsigned short* lB = &Bs[(w * 256 + rnd * 64) * 8];
            __builtin_amdgcn_global_load_lds(
                (const __attribute__((address_space(1))) unsigned int*)gB,
                (__attribute__((address_space(3))) unsigned int*)lB, 16, 0, 0);
        }
        __syncthreads();

        #pragma unroll
        for (int ks = 0; ks < 2; ++ks) {
            bf16x8 a[4], b[4];
            #pragma unroll
            for (int mi = 0; mi < 4; ++mi) {
                int row = wm * 64 + mi * 16 + c15;
                int pc = (ks * 4 + q) ^ (row & 7);
                a[mi] = *(const bf16x8*)&As[row * 64 + pc * 8];
            }
            #pragma unroll
            for (int nj = 0; nj < 4; ++nj) {
                int row = wn * 64 + nj * 16 + c15;
                int pc = (ks * 4 + q) ^ (row & 7);
                b[nj] = *(const bf16x8*)&Bs[row * 64 + pc * 8];
            }
            #pragma unroll
            for (int mi = 0; mi < 4; ++mi)
                #pragma unroll
                for (int nj = 0; nj < 4; ++nj)
                    acc[mi][nj] = __builtin_amdgcn_mfma_f32_16x16x32_bf16(
                        a[mi], b[nj], acc[mi][nj], 0, 0, 0);
        }
        __syncthreads();
    }

    #pragma unroll
    for (int nj = 0; nj < 4; ++nj) {
        int col = colBase + wn * 64 + nj * 16 + c15;
        float bv = bias[col];
        #pragma unroll
        for (int mi = 0; mi < 4; ++mi) {
            int row0 = rowBase + wm * 64 + mi * 16 + q * 4;
            #pragma unroll
            for (int rg = 0; rg < 4; ++rg) {
                C[(size_t)(row0 + rg) * HF + col] = f2bf(acc[mi][nj][rg] + bv);
            }
        }
    }
}

// ---------------------------------------------------------------------------
// K67: fused scatter + edge softmax numerator. One thread per edge: claim CSR
// slot, write src + 8 exp-weights in CSR order, accumulate denom.
// ---------------------------------------------------------------------------
__global__ __launch_bounds__(256) void k67_edge(
        const int* __restrict__ src, const int* __restrict__ dst,
        const float* __restrict__ el, const float* __restrict__ er,
        int* __restrict__ cursor, float* __restrict__ denom,
        int* __restrict__ srcs, float* __restrict__ expw) {
    int e = blockIdx.x * 256 + threadIdx.x;
    if (e >= N_EDGES) return;
    int s = src[e], d = dst[e];
    int pos = atomicAdd(&cursor[d], 1);
    srcs[pos] = s;
    float4 la = *(const float4*)(el + (size_t)s * 8);
    float4 lb = *(const float4*)(el + (size_t)s * 8 + 4);
    float4 ra = *(const float4*)(er + (size_t)d * 8);
    float4 rb = *(const float4*)(er + (size_t)d * 8 + 4);
    float w[8] = { la.x + ra.x, la.y + ra.y, la.z + ra.z, la.w + ra.w,
                   lb.x + rb.x, lb.y + rb.y, lb.z + rb.z, lb.w + rb.w };
    #pragma unroll
    for (int h = 0; h < 8; ++h) {
        float v = w[h];
        v = (v >= 0.f) ? v : NEG * v;
        float ex = expf(v);
        w[h] = ex;
        atomicAdd(&denom[d * 8 + h], ex);
    }
    *(float4*)(expw + (size_t)pos * 8)     = make_float4(w[0], w[1], w[2], w[3]);
    *(float4*)(expw + (size_t)pos * 8 + 4) = make_float4(w[4], w[5], w[6], w[7]);
}

// ---------------------------------------------------------------------------
// K8: aggregation. One WAVE per node; lane owns a 16B uint4 chunk (8 bf16
// features, all within head lane>>3). Srcs preloaded 64-at-a-time + shfl
// broadcast; 4-edge unroll keeps 4 row-gathers in flight. Normalize at end.
// ---------------------------------------------------------------------------
__device__ __forceinline__ void accum8(float* acc, uint4 v, float w) {
    unsigned u;
    u = v.x;
    acc[0] = fmaf(w, __uint_as_float(u << 16), acc[0]);
    acc[1] = fmaf(w, __uint_as_float(u & 0xffff0000u), acc[1]);
    u = v.y;
    acc[2] = fmaf(w, __uint_as_float(u << 16), acc[2]);
    acc[3] = fmaf(w, __uint_as_float(u & 0xffff0000u), acc[3]);
    u = v.z;
    acc[4] = fmaf(w, __uint_as_float(u << 16), acc[4]);
    acc[5] = fmaf(w, __uint_as_float(u & 0xffff0000u), acc[5]);
    u = v.w;
    acc[6] = fmaf(w, __uint_as_float(u << 16), acc[6]);
    acc[7] = fmaf(w, __uint_as_float(u & 0xffff0000u), acc[7]);
}

__global__ __launch_bounds__(256) void k8_agg(
        const int* __restrict__ srcs, const float* __restrict__ expw,
        const int* __restrict__ offs, const int* __restrict__ deg,
        const float* __restrict__ denom,
        const uint4* __restrict__ feat_v,     // bf16 rows: 64 uint4 per row
        float* __restrict__ out) {
    int lane = threadIdx.x & 63;
    int n = blockIdx.x * 4 + (threadIdx.x >> 6);   // grid 12500*4 = 50000 exact
    int start = offs[n], cnt = deg[n];
    int h = lane >> 3;
    float acc[8] = {};
    const float* wp = expw + (size_t)start * 8 + h;

    for (int base = 0; base < cnt; base += 64) {
        int m = cnt - base; if (m > 64) m = 64;
        int s_all = (lane < m) ? srcs[start + base + lane] : 0;
        int i = 0;
        for (; i + 4 <= m; i += 4) {
            int s0 = __shfl(s_all, i, 64),     s1 = __shfl(s_all, i + 1, 64);
            int s2 = __shfl(s_all, i + 2, 64), s3 = __shfl(s_all, i + 3, 64);
            float w0 = wp[(size_t)(base + i) * 8];
            float w1 = wp[(size_t)(base + i + 1) * 8];
            float w2 = wp[(size_t)(base + i + 2) * 8];
            float w3 = wp[(size_t)(base + i + 3) * 8];
            uint4 v0 = feat_v[(size_t)s0 * 64 + lane];
            uint4 v1 = feat_v[(size_t)s1 * 64 + lane];
            uint4 v2 = feat_v[(size_t)s2 * 64 + lane];
            uint4 v3 = feat_v[(size_t)s3 * 64 + lane];
            accum8(acc, v0, w0);
            accum8(acc, v1, w1);
            accum8(acc, v2, w2);
            accum8(acc, v3, w3);
        }
        for (; i < m; ++i) {
            int s0 = __shfl(s_all, i, 64);
            float w0 = wp[(size_t)(base + i) * 8];
            uint4 v0 = feat_v[(size_t)s0 * 64 + lane];
            accum8(acc, v0, w0);
        }
    }

    float dn = 1.f / fmaxf(denom[n * 8 + h], 1e-16f);
    float* op = out + (size_t)n * HF + lane * 8;
    *(float4*)op       = make_float4(acc[0] * dn, acc[1] * dn, acc[2] * dn, acc[3] * dn);
    *(float4*)(op + 4) = make_float4(acc[4] * dn, acc[5] * dn, acc[6] * dn, acc[7] * dn);
}

// ---------------------------------------------------------------------------
extern "C" void kernel_launch(void* const* d_in, const int* in_sizes, int n_in,
                              void* d_out, int out_size, void* d_ws, size_t ws_size,
                              hipStream_t stream) {
    const float* feat   = (const float*)d_in[0];
    const int*   src    = (const int*)d_in[1];
    const int*   dst    = (const int*)d_in[2];
    const float* W_src  = (const float*)d_in[3];
    const float* b_src  = (const float*)d_in[4];
    const float* W_dst  = (const float*)d_in[5];
    const float* b_dst  = (const float*)d_in[6];
    const float* W_val  = (const float*)d_in[7];
    const float* b_val  = (const float*)d_in[8];
    const float* attn_l = (const float*)d_in[9];
    const float* attn_r = (const float*)d_in[10];
    float* out = (float*)d_out;

    char* ws = (char*)d_ws;
    size_t off = 0;
    auto alloc = [&](size_t bytes) -> void* {
        void* p = ws + off;
        off += (bytes + 255) & ~(size_t)255;
        return p;
    };

    unsigned short* feat_bf = (unsigned short*)alloc((size_t)N_PAD * IN_F * 2);
    unsigned short* Wt      = (unsigned short*)alloc((size_t)IN_F * HF * 2);
    unsigned short* feat_v  = (unsigned short*)alloc((size_t)N_PAD * HF * 2);
    float* w_l    = (float*)alloc(4096 * 4);
    float* w_r    = (float*)alloc(4096 * 4);
    float* c_l    = (float*)alloc(8 * 4);
    float* c_r    = (float*)alloc(8 * 4);
    float* el     = (float*)alloc((size_t)N_NODES * 8 * 4);
    float* er     = (float*)alloc((size_t)N_NODES * 8 * 4);
    float* denom  = (float*)alloc((size_t)N_NODES * 8 * 4);
    float* expw   = (float*)alloc((size_t)N_EDGES * 8 * 4);
    int*   deg    = (int*)alloc((size_t)N_NODES * 4);
    int*   offs   = (int*)alloc((size_t)N_NODES * 4);
    int*   cursor = (int*)alloc((size_t)N_NODES * 4);
    int*   srcs   = (int*)alloc((size_t)N_EDGES * 4);
    (void)ws_size; (void)in_sizes; (void)n_in; (void)out_size;

    k0_convert<<<K0_CONV_BLOCKS + K0_ZERO_BLOCKS, 256, 0, stream>>>(feat, feat_bf, denom, deg);
    k14_misc<<<K14_BLOCKS, 256, 0, stream>>>(W_val, Wt, W_src, b_src, W_dst, b_dst,
                                             attn_l, attn_r, w_l, w_r, c_l, c_r, dst, deg);
    k2_el_er<<<(N_NODES + 15) / 16, 256, 0, stream>>>(feat, w_l, w_r, c_l, c_r, el, er);
    kS_scan<<<(N_NODES + 1023) / 1024, 1024, 0, stream>>>(deg, offs, cursor);
    k3_mfma<<<(N_PAD / 128) * 4, 256, 0, stream>>>(feat_bf, Wt, b_val, feat_v);
    k67_edge<<<(N_EDGES + 255) / 256, 256, 0, stream>>>(src, dst, el, er, cursor, denom,
                                                        srcs, expw);
    k8_agg<<<N_NODES / 4, 256, 0, stream>>>(srcs, expw, offs, deg, denom,
                                            (const uint4*)feat_v, out);
}

// Round 4
// 424.621 us; speedup vs baseline: 1.3807x; 1.3807x over previous
//
#include <hip/hip_runtime.h>
#include <math.h>

constexpr int N_NODES = 50000;
constexpr int N_PAD   = 50048;    // 391 * 128, padded rows for tile overrun
constexpr int N_EDGES = 400000;
constexpr int IN_F = 512;
constexpr int HEADS = 8;
constexpr int OUT_F = 64;
constexpr int HF = 512;           // HEADS * OUT_F
constexpr float NEG = 0.2f;

typedef __bf16 bf16x8 __attribute__((ext_vector_type(8)));
typedef float  f32x4  __attribute__((ext_vector_type(4)));

__device__ __forceinline__ unsigned short f2bf(float f) {
    unsigned u = __float_as_uint(f);
    u += 0x7fffu + ((u >> 16) & 1u);   // round-to-nearest-even (inputs finite)
    return (unsigned short)(u >> 16);
}
__device__ __forceinline__ unsigned packbf2(float lo, float hi) {
    return (unsigned)f2bf(lo) | ((unsigned)f2bf(hi) << 16);
}

// ---------------------------------------------------------------------------
// K0: feat fp32 -> bf16; tail blocks zero deg.
// ---------------------------------------------------------------------------
constexpr int K0_CONV_BLOCKS = 12500;                 // 12500*256*8 = 25.6M elems
constexpr int K0_ZERO_BLOCKS = (N_NODES + 255) / 256; // 196

__global__ __launch_bounds__(256) void k0_convert(const float* __restrict__ in,
                                                  unsigned short* __restrict__ out,
                                                  int* __restrict__ deg) {
    int b = blockIdx.x;
    if (b < K0_CONV_BLOCKS) {
        int idx = b * 256 + threadIdx.x;
        size_t base = (size_t)idx * 8;
        float4 a = *(const float4*)(in + base);
        float4 c = *(const float4*)(in + base + 4);
        uint4 v;
        v.x = packbf2(a.x, a.y);
        v.y = packbf2(a.z, a.w);
        v.z = packbf2(c.x, c.y);
        v.w = packbf2(c.z, c.w);
        *(uint4*)(out + base) = v;
    } else {
        int idx = (b - K0_CONV_BLOCKS) * 256 + threadIdx.x;
        if (idx < N_NODES) deg[idx] = 0;
    }
}

// ---------------------------------------------------------------------------
// K14: merged dispatch — [0,256): W_val transpose->bf16; [256,289): fold
// attention vectors; [289,...): dst-degree histogram.
// ---------------------------------------------------------------------------
constexpr int K14_HIST0 = 289;
constexpr int K14_BLOCKS = K14_HIST0 + (N_EDGES + 255) / 256;   // 289 + 1563

__global__ __launch_bounds__(256) void k14_misc(
        const float* __restrict__ W_val, unsigned short* __restrict__ Wt,
        const float* __restrict__ W_src, const float* __restrict__ b_src,
        const float* __restrict__ W_dst, const float* __restrict__ b_dst,
        const float* __restrict__ attn_l, const float* __restrict__ attn_r,
        float* __restrict__ w_l, float* __restrict__ w_r,
        float* __restrict__ c_l, float* __restrict__ c_r,
        const int* __restrict__ dst, int* __restrict__ deg) {
    __shared__ float tile[32][33];
    int b = blockIdx.x, t = threadIdx.x;
    if (b < 256) {
        int bi = b >> 4, bj = b & 15;
        for (int i = t; i < 1024; i += 256) {
            int r = i >> 5, c = i & 31;
            tile[r][c] = W_val[(size_t)(bi * 32 + r) * HF + bj * 32 + c];
        }
        __syncthreads();
        for (int i = t; i < 1024; i += 256) {
            int r = i >> 5, c = i & 31;
            Wt[(size_t)(bj * 32 + r) * IN_F + bi * 32 + c] = f2bf(tile[c][r]);
        }
    } else if (b < K14_HIST0) {
        int gid = (b - 256) * 256 + t;
        if (gid < 4096) {
            int k = gid >> 3, h = gid & 7;
            float s = 0.f;
            #pragma unroll 8
            for (int f = 0; f < OUT_F; ++f) s += W_src[k * HF + h * OUT_F + f] * attn_l[h * OUT_F + f];
            w_l[k * 8 + h] = s;
        } else if (gid < 8192) {
            int g = gid - 4096;
            int k = g >> 3, h = g & 7;
            float s = 0.f;
            #pragma unroll 8
            for (int f = 0; f < OUT_F; ++f) s += W_dst[k * HF + h * OUT_F + f] * attn_r[h * OUT_F + f];
            w_r[k * 8 + h] = s;
        } else if (gid < 8192 + 16) {
            int g = gid - 8192;
            int h = g & 7;
            float s = 0.f;
            if (g < 8) {
                for (int f = 0; f < OUT_F; ++f) s += b_src[h * OUT_F + f] * attn_l[h * OUT_F + f];
                c_l[h] = s;
            } else {
                for (int f = 0; f < OUT_F; ++f) s += b_dst[h * OUT_F + f] * attn_r[h * OUT_F + f];
                c_r[h] = s;
            }
        }
    } else {
        int e = (b - K14_HIST0) * 256 + t;
        if (e < N_EDGES) atomicAdd(&deg[dst[e]], 1);
    }
}

// ---------------------------------------------------------------------------
// K2: el/er = feat @ w_l/w_r + c. 16 threads per node; w in LDS.
// ---------------------------------------------------------------------------
__global__ __launch_bounds__(256) void k2_el_er(
        const float* __restrict__ feat,
        const float* __restrict__ w_l, const float* __restrict__ w_r,
        const float* __restrict__ c_l, const float* __restrict__ c_r,
        float* __restrict__ el, float* __restrict__ er) {
    __shared__ float swl[4096];
    __shared__ float swr[4096];
    int t = threadIdx.x;
    for (int i = t; i < 4096; i += 256) { swl[i] = w_l[i]; swr[i] = w_r[i]; }
    __syncthreads();

    int node = blockIdx.x * 16 + (t >> 4);
    if (node >= N_NODES) return;
    int sub = t & 15, h = sub & 7, side = sub >> 3;

    const float* w = side ? swr : swl;
    float acc = side ? c_r[h] : c_l[h];
    const float* frow = feat + (size_t)node * IN_F;
    for (int k = 0; k < IN_F; k += 4) {
        float4 f = *(const float4*)(frow + k);
        acc = fmaf(f.x, w[(k + 0) * 8 + h], acc);
        acc = fmaf(f.y, w[(k + 1) * 8 + h], acc);
        acc = fmaf(f.z, w[(k + 2) * 8 + h], acc);
        acc = fmaf(f.w, w[(k + 3) * 8 + h], acc);
    }
    if (side) er[node * 8 + h] = acc; else el[node * 8 + h] = acc;
}

// ---------------------------------------------------------------------------
// KS: single-dispatch exclusive scan (redundant-prefix per block, no serial).
// ---------------------------------------------------------------------------
__global__ __launch_bounds__(1024) void kS_scan(const int* __restrict__ deg,
                                                int* __restrict__ offs,
                                                int* __restrict__ cursor) {
    __shared__ int wsum[16];
    __shared__ int base_s;
    int b = blockIdx.x, t = threadIdx.x;
    int lane = t & 63, wid = t >> 6;

    int pre = 0;
    for (int i = t; i < b * 1024; i += 1024) pre += deg[i];
    #pragma unroll
    for (int off = 32; off; off >>= 1) pre += __shfl_down(pre, (unsigned)off, 64);
    if (lane == 0) wsum[wid] = pre;
    __syncthreads();
    if (t == 0) {
        int s = 0;
        for (int i = 0; i < 16; ++i) s += wsum[i];
        base_s = s;
    }
    __syncthreads();
    int base = base_s;
    __syncthreads();

    int i = b * 1024 + t;
    int v = (i < N_NODES) ? deg[i] : 0;
    int x = v;
    #pragma unroll
    for (int off = 1; off < 64; off <<= 1) {
        int y = __shfl_up(x, (unsigned)off, 64);
        if (lane >= off) x += y;
    }
    if (lane == 63) wsum[wid] = x;
    __syncthreads();
    if (wid == 0) {
        int s = (lane < 16) ? wsum[lane] : 0;
        #pragma unroll
        for (int off = 1; off < 16; off <<= 1) {
            int y = __shfl_up(s, (unsigned)off, 64);
            if (lane >= off) s += y;
        }
        if (lane < 16) wsum[lane] = s;
    }
    __syncthreads();
    int woff = wid ? wsum[wid - 1] : 0;
    if (i < N_NODES) {
        int excl = base + woff + x - v;
        offs[i] = excl;
        cursor[i] = excl;
    }
}

// ---------------------------------------------------------------------------
// K3: feat_v = feat @ W_val + b_val via bf16 MFMA (m97 structure, validated)
// ---------------------------------------------------------------------------
__global__ __launch_bounds__(256) void k3_mfma(
        const unsigned short* __restrict__ Abf,
        const unsigned short* __restrict__ Bbf,
        const float* __restrict__ bias,
        unsigned short* __restrict__ C) {
    __shared__ unsigned short As[128 * 64];
    __shared__ unsigned short Bs[128 * 64];
    int tid = threadIdx.x;
    int w = tid >> 6, lane = tid & 63;
    int bm = blockIdx.x >> 2, bn = blockIdx.x & 3;
    int rowBase = bm * 128, colBase = bn * 128;
    int wm = w >> 1, wn = w & 1;
    int c15 = lane & 15, q = lane >> 4;

    f32x4 acc[4][4] = {};

    for (int k0 = 0; k0 < IN_F; k0 += 64) {
        #pragma unroll
        for (int rnd = 0; rnd < 4; ++rnd) {
            int e = w * 256 + rnd * 64 + lane;
            int r = e >> 3, p = e & 7;
            int lc = p ^ (r & 7);                  // XOR chunk swizzle
            const unsigned short* gA = Abf + (size_t)(rowBase + r) * IN_F + k0 + lc * 8;
            unsigned short* lA = &As[(w * 256 + rnd * 64) * 8];
            __builtin_amdgcn_global_load_lds(
                (const __attribute__((address_space(1))) unsigned int*)gA,
                (__attribute__((address_space(3))) unsigned int*)lA, 16, 0, 0);
            const unsigned short* gB = Bbf + (size_t)(colBase + r) * IN_F + k0 + lc * 8;
            unsigned short* lB = &Bs[(w * 256 + rnd * 64) * 8];
            __builtin_amdgcn_global_load_lds(
                (const __attribute__((address_space(1))) unsigned int*)gB,
                (__attribute__((address_space(3))) unsigned int*)lB, 16, 0, 0);
        }
        __syncthreads();

        #pragma unroll
        for (int ks = 0; ks < 2; ++ks) {
            bf16x8 a[4], b[4];
            #pragma unroll
            for (int mi = 0; mi < 4; ++mi) {
                int row = wm * 64 + mi * 16 + c15;
                int pc = (ks * 4 + q) ^ (row & 7);
                a[mi] = *(const bf16x8*)&As[row * 64 + pc * 8];
            }
            #pragma unroll
            for (int nj = 0; nj < 4; ++nj) {
                int row = wn * 64 + nj * 16 + c15;
                int pc = (ks * 4 + q) ^ (row & 7);
                b[nj] = *(const bf16x8*)&Bs[row * 64 + pc * 8];
            }
            #pragma unroll
            for (int mi = 0; mi < 4; ++mi)
                #pragma unroll
                for (int nj = 0; nj < 4; ++nj)
                    acc[mi][nj] = __builtin_amdgcn_mfma_f32_16x16x32_bf16(
                        a[mi], b[nj], acc[mi][nj], 0, 0, 0);
        }
        __syncthreads();
    }

    #pragma unroll
    for (int nj = 0; nj < 4; ++nj) {
        int col = colBase + wn * 64 + nj * 16 + c15;
        float bv = bias[col];
        #pragma unroll
        for (int mi = 0; mi < 4; ++mi) {
            int row0 = rowBase + wm * 64 + mi * 16 + q * 4;
            #pragma unroll
            for (int rg = 0; rg < 4; ++rg) {
                C[(size_t)(row0 + rg) * HF + col] = f2bf(acc[mi][nj][rg] + bv);
            }
        }
    }
}

// ---------------------------------------------------------------------------
// K6: counting-sort scatter ONLY (4B payload — minimal scattered write).
// ---------------------------------------------------------------------------
__global__ __launch_bounds__(256) void k6_scatter(
        const int* __restrict__ src, const int* __restrict__ dst,
        int* __restrict__ cursor, int* __restrict__ srcs) {
    int e = blockIdx.x * 256 + threadIdx.x;
    if (e < N_EDGES) {
        int pos = atomicAdd(&cursor[dst[e]], 1);
        srcs[pos] = src[e];
    }
}

// ---------------------------------------------------------------------------
// K8: fused edge-softmax + aggregation. One WAVE per node; lane owns a 16B
// uint4 chunk (8 bf16 feats, one head = lane>>3). Per edge: gather
// el[s*8+h] (L2-resident, broadcast in head group), w = exp(leaky(el+er)),
// accumulate numerator (registers) and denominator (per-lane running sum).
// 8-edge unroll keeps 8 KB/wave of gathers in flight. Atomic-free.
// ---------------------------------------------------------------------------
__device__ __forceinline__ void accum8(float* acc, uint4 v, float w) {
    unsigned u;
    u = v.x;
    acc[0] = fmaf(w, __uint_as_float(u << 16), acc[0]);
    acc[1] = fmaf(w, __uint_as_float(u & 0xffff0000u), acc[1]);
    u = v.y;
    acc[2] = fmaf(w, __uint_as_float(u << 16), acc[2]);
    acc[3] = fmaf(w, __uint_as_float(u & 0xffff0000u), acc[3]);
    u = v.z;
    acc[4] = fmaf(w, __uint_as_float(u << 16), acc[4]);
    acc[5] = fmaf(w, __uint_as_float(u & 0xffff0000u), acc[5]);
    u = v.w;
    acc[6] = fmaf(w, __uint_as_float(u << 16), acc[6]);
    acc[7] = fmaf(w, __uint_as_float(u & 0xffff0000u), acc[7]);
}

__global__ __launch_bounds__(256) void k8_agg(
        const int* __restrict__ srcs, const int* __restrict__ offs,
        const int* __restrict__ deg,
        const float* __restrict__ el, const float* __restrict__ er,
        const uint4* __restrict__ feat_v,     // bf16 rows: 64 uint4 per row
        float* __restrict__ out) {
    int lane = threadIdx.x & 63;
    int n = blockIdx.x * 4 + (threadIdx.x >> 6);   // grid 12500*4 = 50000 exact
    int start = offs[n], cnt = deg[n];
    int h = lane >> 3;
    float erh = er[(size_t)n * 8 + h];
    float acc[8] = {};
    float dsum = 0.f;

    for (int base = 0; base < cnt; base += 64) {
        int m = cnt - base; if (m > 64) m = 64;
        int s_all = (lane < m) ? srcs[start + base + lane] : 0;
        int i = 0;
        for (; i + 8 <= m; i += 8) {
            int s[8]; uint4 v[8]; float e[8];
            #pragma unroll
            for (int j = 0; j < 8; ++j) s[j] = __shfl(s_all, i + j, 64);
            #pragma unroll
            for (int j = 0; j < 8; ++j) v[j] = feat_v[(size_t)s[j] * 64 + lane];
            #pragma unroll
            for (int j = 0; j < 8; ++j) e[j] = el[(size_t)s[j] * 8 + h];
            #pragma unroll
            for (int j = 0; j < 8; ++j) {
                float x = e[j] + erh;
                x = (x >= 0.f) ? x : NEG * x;
                float w = __expf(x);
                dsum += w;
                accum8(acc, v[j], w);
            }
        }
        for (; i < m; ++i) {
            int s0 = __shfl(s_all, i, 64);
            uint4 v0 = feat_v[(size_t)s0 * 64 + lane];
            float x = el[(size_t)s0 * 8 + h] + erh;
            x = (x >= 0.f) ? x : NEG * x;
            float w = __expf(x);
            dsum += w;
            accum8(acc, v0, w);
        }
    }

    float dn = 1.f / fmaxf(dsum, 1e-16f);
    float* op = out + (size_t)n * HF + lane * 8;
    *(float4*)op       = make_float4(acc[0] * dn, acc[1] * dn, acc[2] * dn, acc[3] * dn);
    *(float4*)(op + 4) = make_float4(acc[4] * dn, acc[5] * dn, acc[6] * dn, acc[7] * dn);
}

// ---------------------------------------------------------------------------
extern "C" void kernel_launch(void* const* d_in, const int* in_sizes, int n_in,
                              void* d_out, int out_size, void* d_ws, size_t ws_size,
                              hipStream_t stream) {
    const float* feat   = (const float*)d_in[0];
    const int*   src    = (const int*)d_in[1];
    const int*   dst    = (const int*)d_in[2];
    const float* W_src  = (const float*)d_in[3];
    const float* b_src  = (const float*)d_in[4];
    const float* W_dst  = (const float*)d_in[5];
    const float* b_dst  = (const float*)d_in[6];
    const float* W_val  = (const float*)d_in[7];
    const float* b_val  = (const float*)d_in[8];
    const float* attn_l = (const float*)d_in[9];
    const float* attn_r = (const float*)d_in[10];
    float* out = (float*)d_out;

    char* ws = (char*)d_ws;
    size_t off = 0;
    auto alloc = [&](size_t bytes) -> void* {
        void* p = ws + off;
        off += (bytes + 255) & ~(size_t)255;
        return p;
    };

    unsigned short* feat_bf = (unsigned short*)alloc((size_t)N_PAD * IN_F * 2);
    unsigned short* Wt      = (unsigned short*)alloc((size_t)IN_F * HF * 2);
    unsigned short* feat_v  = (unsigned short*)alloc((size_t)N_PAD * HF * 2);
    float* w_l    = (float*)alloc(4096 * 4);
    float* w_r    = (float*)alloc(4096 * 4);
    float* c_l    = (float*)alloc(8 * 4);
    float* c_r    = (float*)alloc(8 * 4);
    float* el     = (float*)alloc((size_t)N_NODES * 8 * 4);
    float* er     = (float*)alloc((size_t)N_NODES * 8 * 4);
    int*   deg    = (int*)alloc((size_t)N_NODES * 4);
    int*   offs   = (int*)alloc((size_t)N_NODES * 4);
    int*   cursor = (int*)alloc((size_t)N_NODES * 4);
    int*   srcs   = (int*)alloc((size_t)N_EDGES * 4);
    (void)ws_size; (void)in_sizes; (void)n_in; (void)out_size;

    k0_convert<<<K0_CONV_BLOCKS + K0_ZERO_BLOCKS, 256, 0, stream>>>(feat, feat_bf, deg);
    k14_misc<<<K14_BLOCKS, 256, 0, stream>>>(W_val, Wt, W_src, b_src, W_dst, b_dst,
                                             attn_l, attn_r, w_l, w_r, c_l, c_r, dst, deg);
    k2_el_er<<<(N_NODES + 15) / 16, 256, 0, stream>>>(feat, w_l, w_r, c_l, c_r, el, er);
    kS_scan<<<(N_NODES + 1023) / 1024, 1024, 0, stream>>>(deg, offs, cursor);
    k3_mfma<<<(N_PAD / 128) * 4, 256, 0, stream>>>(feat_bf, Wt, b_val, feat_v);
    k6_scatter<<<(N_EDGES + 255) / 256, 256, 0, stream>>>(src, dst, cursor, srcs);
    k8_agg<<<N_NODES / 4, 256, 0, stream>>>(srcs, offs, deg, el, er,
                                            (const uint4*)feat_v, out);
}